// Round 1
// baseline (376.677 us; speedup 1.0000x reference)
//
#include <hip/hip_runtime.h>

// Problem constants
#define B_   2
#define S_   2048
#define H_   2048
#define NH_  16
#define G_   4
#define HD_  128
#define KV_  512

typedef __attribute__((ext_vector_type(8))) short bf16x8;
typedef __attribute__((ext_vector_type(4))) float f32x4;

__device__ __forceinline__ unsigned short f2bf(float f) {
    unsigned u = __float_as_uint(f);
    u += 0x7fff + ((u >> 16) & 1);   // RNE
    return (unsigned short)(u >> 16);
}

// ---------------- fp32 -> bf16 elementwise ----------------
__global__ void k_cvt_bf16(const float* __restrict__ in, unsigned short* __restrict__ out, int n4) {
    int i = blockIdx.x * blockDim.x + threadIdx.x;
    if (i >= n4) return;
    float4 v = ((const float4*)in)[i];
    ushort4 o;
    o.x = f2bf(v.x); o.y = f2bf(v.y); o.z = f2bf(v.z); o.w = f2bf(v.w);
    ((ushort4*)out)[i] = o;
}

// ---------------- fp32 [R][C] -> bf16 [C][R] (weight transpose+convert) ----------------
__global__ void k_transpose_cvt(const float* __restrict__ in, unsigned short* __restrict__ out,
                                int R, int C) {
    __shared__ float t[32][33];
    int c0 = blockIdx.x * 32, r0 = blockIdx.y * 32;
    int tx = threadIdx.x, ty = threadIdx.y;   // 32 x 8
#pragma unroll
    for (int i = 0; i < 4; ++i)
        t[ty + i*8][tx] = in[(size_t)(r0 + ty + i*8) * C + c0 + tx];
    __syncthreads();
#pragma unroll
    for (int i = 0; i < 4; ++i)
        out[(size_t)(c0 + ty + i*8) * R + r0 + tx] = f2bf(t[tx][ty + i*8]);
}

// ---------------- bf16 V [B*S][KV] -> V^T [B][KV][S] ----------------
__global__ void k_transpose_v(const unsigned short* __restrict__ in, unsigned short* __restrict__ out) {
    __shared__ unsigned short t[32][33];
    int b = blockIdx.z;
    int c0 = blockIdx.x * 32, s0 = blockIdx.y * 32;
    int tx = threadIdx.x, ty = threadIdx.y;
#pragma unroll
    for (int i = 0; i < 4; ++i)
        t[ty + i*8][tx] = in[((size_t)b * S_ + s0 + ty + i*8) * KV_ + c0 + tx];
    __syncthreads();
#pragma unroll
    for (int i = 0; i < 4; ++i)
        out[((size_t)b * KV_ + c0 + ty + i*8) * S_ + s0 + tx] = t[tx][ty + i*8];
}

// ---------------- bf16 GEMM: C[M,N] = A[M,K] * Bt[N,K]^T + bias ----------------
// m97-structure: 128x128 tile, BK=64, global_load_lds w16, both-sides chunk XOR swizzle.
#define GLDS16(gsrc, ldst)                                                            \
    __builtin_amdgcn_global_load_lds(                                                 \
        (const __attribute__((address_space(1))) void*)(gsrc),                        \
        (__attribute__((address_space(3))) void*)(ldst), 16, 0, 0)

template <bool BF16OUT>
__global__ __launch_bounds__(256) void k_gemm_bt(
    const unsigned short* __restrict__ A, const unsigned short* __restrict__ Bt,
    const float* __restrict__ bias, void* __restrict__ Cout, int M, int N, int K) {
    __shared__ __align__(16) unsigned short As[128 * 64];
    __shared__ __align__(16) unsigned short Bs[128 * 64];
    const int tid = threadIdx.x, lane = tid & 63, w = tid >> 6;
    const int l15 = lane & 15, l4 = lane >> 4;
    const int wr = w >> 1, wc = w & 1;
    const int m0 = blockIdx.x * 128, n0 = blockIdx.y * 128;
    f32x4 acc[4][4] = {};

    for (int kt = 0; kt < K; kt += 64) {
        __syncthreads();
        // stage A tile: 128 rows x 64 (8x 16B chunks per row); LDS position p holds
        // global chunk (row=p>>3, c=(p&7)^(row&7)) -> conflict-free swizzled reads.
#pragma unroll
        for (int i = 0; i < 4; ++i) {
            int p = (w * 4 + i) * 64 + lane;
            int row = p >> 3, c = (p & 7) ^ (row & 7);
            GLDS16(A + (size_t)(m0 + row) * K + kt + c * 8, As + (size_t)(w * 4 + i) * 512);
        }
#pragma unroll
        for (int i = 0; i < 4; ++i) {
            int p = (w * 4 + i) * 64 + lane;
            int row = p >> 3, c = (p & 7) ^ (row & 7);
            GLDS16(Bt + (size_t)(n0 + row) * K + kt + c * 8, Bs + (size_t)(w * 4 + i) * 512);
        }
        __syncthreads();
#pragma unroll
        for (int ks = 0; ks < 2; ++ks) {
            bf16x8 af[4], bfr[4];
#pragma unroll
            for (int m = 0; m < 4; ++m) {
                int row = wr * 64 + m * 16 + l15;
                int ch = (ks * 4 + l4) ^ (row & 7);
                af[m] = *(const bf16x8*)(As + row * 64 + ch * 8);
            }
#pragma unroll
            for (int n = 0; n < 4; ++n) {
                int row = wc * 64 + n * 16 + l15;
                int ch = (ks * 4 + l4) ^ (row & 7);
                bfr[n] = *(const bf16x8*)(Bs + row * 64 + ch * 8);
            }
#pragma unroll
            for (int m = 0; m < 4; ++m)
#pragma unroll
                for (int n = 0; n < 4; ++n)
                    acc[m][n] = __builtin_amdgcn_mfma_f32_16x16x32_bf16(af[m], bfr[n], acc[m][n], 0, 0, 0);
        }
    }
    // epilogue: C row = (l4*4 + reg), col = l15  [m89-verified layout]
#pragma unroll
    for (int m = 0; m < 4; ++m) {
        int row = m0 + wr * 64 + m * 16 + l4 * 4;
#pragma unroll
        for (int n = 0; n < 4; ++n) {
            int col = n0 + wc * 64 + n * 16 + l15;
            float bv = bias[col];
#pragma unroll
            for (int r = 0; r < 4; ++r) {
                float v = acc[m][n][r] + bv;
                if (BF16OUT)
                    ((unsigned short*)Cout)[(size_t)(row + r) * N + col] = f2bf(v);
                else
                    ((float*)Cout)[(size_t)(row + r) * N + col] = v;
            }
        }
    }
}

// ---------------- causal GQA flash attention ----------------
// QBLK=128 (4 waves x 32 rows), KBLK=64, D=128. Q in regs; K,V^T,P in LDS (padded).
__global__ __launch_bounds__(256) void k_flash(
    const unsigned short* __restrict__ Q,   // [B*S][H]
    const unsigned short* __restrict__ Km,  // [B*S][KV]
    const unsigned short* __restrict__ VT,  // [B][KV][S]
    unsigned short* __restrict__ Oa) {      // [B*S][H]
    __shared__ __align__(16) unsigned short Ks[64][136];    // K tile, +8 pad
    __shared__ __align__(16) unsigned short Vs[128][72];    // V^T tile, +8 pad
    __shared__ __align__(16) unsigned short Ps[4][32][72];  // per-wave P
    const int tid = threadIdx.x, lane = tid & 63, w = tid >> 6;
    const int l15 = lane & 15, l4 = lane >> 4;
    const int qt = blockIdx.x;
    const int bh = blockIdx.y;
    const int b = bh >> 4, nh = bh & 15, g = nh >> 2;
    const int q0 = qt * 128;
    const int qbase = q0 + w * 32;

    // Q fragments in registers (loaded once)
    bf16x8 qf[2][4];
#pragma unroll
    for (int mr = 0; mr < 2; ++mr)
#pragma unroll
        for (int kb = 0; kb < 4; ++kb)
            qf[mr][kb] = *(const bf16x8*)(Q + (size_t)(b * S_ + qbase + mr * 16 + l15) * H_ +
                                          nh * HD_ + kb * 32 + l4 * 8);

    f32x4 o[2][8] = {};
    float mrow[2][4], lrow[2][4];
#pragma unroll
    for (int mr = 0; mr < 2; ++mr)
#pragma unroll
        for (int r = 0; r < 4; ++r) { mrow[mr][r] = -1e30f; lrow[mr][r] = 0.f; }

    const int nkt = (q0 + 128) >> 6;   // causal: only tiles up to the diagonal
    for (int kt = 0; kt < nkt; ++kt) {
        const int kv0 = kt * 64;
        __syncthreads();
        // stage K tile [64][128] (16 chunks/row)
#pragma unroll
        for (int i = 0; i < 4; ++i) {
            int f = i * 256 + tid;
            int row = f >> 4, c = f & 15;
            *(bf16x8*)(&Ks[row][c * 8]) =
                *(const bf16x8*)(Km + (size_t)(b * S_ + kv0 + row) * KV_ + g * HD_ + c * 8);
        }
        // stage V^T tile [128 d][64 k] (8 chunks/row)
#pragma unroll
        for (int i = 0; i < 4; ++i) {
            int f = i * 256 + tid;
            int row = f >> 3, c = f & 7;
            *(bf16x8*)(&Vs[row][c * 8]) =
                *(const bf16x8*)(VT + ((size_t)b * KV_ + g * HD_ + row) * S_ + kv0 + c * 8);
        }
        __syncthreads();
        // S = Q K^T  (A=Q rows, B=K^T: b-frag holds K[kcol][d] k-contiguous)
        f32x4 s[2][4] = {};
#pragma unroll
        for (int kb = 0; kb < 4; ++kb) {
            bf16x8 kf[4];
#pragma unroll
            for (int n = 0; n < 4; ++n)
                kf[n] = *(const bf16x8*)(&Ks[n * 16 + l15][kb * 32 + l4 * 8]);
#pragma unroll
            for (int mr = 0; mr < 2; ++mr)
#pragma unroll
                for (int n = 0; n < 4; ++n)
                    s[mr][n] = __builtin_amdgcn_mfma_f32_16x16x32_bf16(qf[mr][kb], kf[n], s[mr][n], 0, 0, 0);
        }
        // scale + causal mask (k > q -> -1e30)
        const float sc = 0.08838834764831843f;  // 1/sqrt(128)
#pragma unroll
        for (int mr = 0; mr < 2; ++mr)
#pragma unroll
            for (int r = 0; r < 4; ++r) {
                int qrow = qbase + mr * 16 + l4 * 4 + r;
#pragma unroll
                for (int n = 0; n < 4; ++n) {
                    int kcol = kv0 + n * 16 + l15;
                    float v = s[mr][n][r] * sc;
                    s[mr][n][r] = (kcol <= qrow) ? v : -1e30f;
                }
            }
        // online softmax: row lives in 16-lane group (col=l15), rows = l4*4+r
        float sf[2][4];
#pragma unroll
        for (int mr = 0; mr < 2; ++mr)
#pragma unroll
            for (int r = 0; r < 4; ++r) {
                float vm = fmaxf(fmaxf(s[mr][0][r], s[mr][1][r]), fmaxf(s[mr][2][r], s[mr][3][r]));
                vm = fmaxf(vm, __shfl_xor(vm, 1));
                vm = fmaxf(vm, __shfl_xor(vm, 2));
                vm = fmaxf(vm, __shfl_xor(vm, 4));
                vm = fmaxf(vm, __shfl_xor(vm, 8));
                float mn = fmaxf(mrow[mr][r], vm);
                sf[mr][r] = __expf(mrow[mr][r] - mn);
                mrow[mr][r] = mn;
            }
        float rs[2][4] = {{0, 0, 0, 0}, {0, 0, 0, 0}};
#pragma unroll
        for (int mr = 0; mr < 2; ++mr)
#pragma unroll
            for (int n = 0; n < 4; ++n)
#pragma unroll
                for (int r = 0; r < 4; ++r) {
                    float p = __expf(s[mr][n][r] - mrow[mr][r]);
                    s[mr][n][r] = p;
                    rs[mr][r] += p;
                }
#pragma unroll
        for (int mr = 0; mr < 2; ++mr)
#pragma unroll
            for (int r = 0; r < 4; ++r) {
                float t = rs[mr][r];
                t += __shfl_xor(t, 1); t += __shfl_xor(t, 2);
                t += __shfl_xor(t, 4); t += __shfl_xor(t, 8);
                lrow[mr][r] = lrow[mr][r] * sf[mr][r] + t;
            }
        // rescale O
#pragma unroll
        for (int mr = 0; mr < 2; ++mr)
#pragma unroll
            for (int nc = 0; nc < 8; ++nc) {
                f32x4 t = o[mr][nc];
                t[0] *= sf[mr][0]; t[1] *= sf[mr][1]; t[2] *= sf[mr][2]; t[3] *= sf[mr][3];
                o[mr][nc] = t;
            }
        // P -> LDS (bf16), C-layout scatter
#pragma unroll
        for (int mr = 0; mr < 2; ++mr)
#pragma unroll
            for (int n = 0; n < 4; ++n)
#pragma unroll
                for (int r = 0; r < 4; ++r)
                    Ps[w][mr * 16 + l4 * 4 + r][n * 16 + l15] = f2bf(s[mr][n][r]);
        // O += P V  (A=P from LDS in a-frag layout, B=V via V^T tile)
#pragma unroll
        for (int kb = 0; kb < 2; ++kb) {
            bf16x8 pf[2];
            pf[0] = *(const bf16x8*)(&Ps[w][l15][kb * 32 + l4 * 8]);
            pf[1] = *(const bf16x8*)(&Ps[w][16 + l15][kb * 32 + l4 * 8]);
#pragma unroll
            for (int nc = 0; nc < 8; ++nc) {
                bf16x8 vf = *(const bf16x8*)(&Vs[nc * 16 + l15][kb * 32 + l4 * 8]);
                o[0][nc] = __builtin_amdgcn_mfma_f32_16x16x32_bf16(pf[0], vf, o[0][nc], 0, 0, 0);
                o[1][nc] = __builtin_amdgcn_mfma_f32_16x16x32_bf16(pf[1], vf, o[1][nc], 0, 0, 0);
            }
        }
    }
    // epilogue: divide by l, store bf16
#pragma unroll
    for (int mr = 0; mr < 2; ++mr)
#pragma unroll
        for (int r = 0; r < 4; ++r) {
            float inv = 1.0f / lrow[mr][r];
            int qrow = qbase + mr * 16 + l4 * 4 + r;
            size_t base = (size_t)(b * S_ + qrow) * H_ + nh * HD_;
#pragma unroll
            for (int nc = 0; nc < 8; ++nc)
                Oa[base + nc * 16 + l15] = f2bf(o[mr][nc][r] * inv);
        }
}

// ---------------- launch ----------------
extern "C" void kernel_launch(void* const* d_in, const int* in_sizes, int n_in,
                              void* d_out, int out_size, void* d_ws, size_t ws_size,
                              hipStream_t stream) {
    const float* X  = (const float*)d_in[0];
    const float* Wq = (const float*)d_in[1];
    const float* bq = (const float*)d_in[2];
    const float* Wk = (const float*)d_in[3];
    const float* bk = (const float*)d_in[4];
    const float* Wv = (const float*)d_in[5];
    const float* bv = (const float*)d_in[6];
    const float* Wo = (const float*)d_in[7];
    const float* bo = (const float*)d_in[8];
    float* out = (float*)d_out;

    if (ws_size < 83886080) return;  // need 80 MB
    char* ws = (char*)d_ws;
    unsigned short* Xb  = (unsigned short*)(ws);
    unsigned short* WqT = (unsigned short*)(ws + 16777216);
    unsigned short* WkT = (unsigned short*)(ws + 25165824);
    unsigned short* WvT = (unsigned short*)(ws + 27262976);
    unsigned short* WoT = (unsigned short*)(ws + 29360128);
    unsigned short* Qb  = (unsigned short*)(ws + 37748736);
    unsigned short* Kb  = (unsigned short*)(ws + 54525952);
    unsigned short* Vb  = (unsigned short*)(ws + 58720256);
    unsigned short* VbT = (unsigned short*)(ws + 62914560);
    unsigned short* AOb = (unsigned short*)(ws + 67108864);

    k_cvt_bf16<<<(B_ * S_ * H_ / 4 + 255) / 256, 256, 0, stream>>>(X, Xb, B_ * S_ * H_ / 4);
    k_transpose_cvt<<<dim3(H_ / 32, H_ / 32), dim3(32, 8), 0, stream>>>(Wq, WqT, H_, H_);
    k_transpose_cvt<<<dim3(KV_ / 32, H_ / 32), dim3(32, 8), 0, stream>>>(Wk, WkT, H_, KV_);
    k_transpose_cvt<<<dim3(KV_ / 32, H_ / 32), dim3(32, 8), 0, stream>>>(Wv, WvT, H_, KV_);
    k_transpose_cvt<<<dim3(H_ / 32, H_ / 32), dim3(32, 8), 0, stream>>>(Wo, WoT, H_, H_);

    k_gemm_bt<true><<<dim3(32, 16), 256, 0, stream>>>(Xb, WqT, bq, Qb, 4096, 2048, 2048);
    k_gemm_bt<true><<<dim3(32, 4), 256, 0, stream>>>(Xb, WkT, bk, Kb, 4096, 512, 2048);
    k_gemm_bt<true><<<dim3(32, 4), 256, 0, stream>>>(Xb, WvT, bv, Vb, 4096, 512, 2048);

    k_transpose_v<<<dim3(KV_ / 32, S_ / 32, B_), dim3(32, 8), 0, stream>>>(Vb, VbT);
    k_flash<<<dim3(16, 32), 256, 0, stream>>>(Qb, Kb, VbT, AOb);

    k_gemm_bt<false><<<dim3(32, 16), 256, 0, stream>>>(AOb, WoT, bo, out, 4096, 2048, 2048);
}

// Round 2
// 257.633 us; speedup vs baseline: 1.4621x; 1.4621x over previous
//
#include <hip/hip_runtime.h>

// Problem constants
#define B_   2
#define S_   2048
#define H_   2048
#define NH_  16
#define G_   4
#define HD_  128
#define KV_  512
#define HQKV 3072   // fused Q|K|V output width

typedef __attribute__((ext_vector_type(8))) short bf16x8;
typedef __attribute__((ext_vector_type(4))) float f32x4;

__device__ __forceinline__ unsigned short f2bf(float f) {
    unsigned u = __float_as_uint(f);
    u += 0x7fff + ((u >> 16) & 1);   // RNE
    return (unsigned short)(u >> 16);
}

// ---------------- fp32 -> bf16 elementwise ----------------
__global__ void k_cvt_bf16(const float* __restrict__ in, unsigned short* __restrict__ out, int n4) {
    int i = blockIdx.x * blockDim.x + threadIdx.x;
    if (i >= n4) return;
    float4 v = ((const float4*)in)[i];
    ushort4 o;
    o.x = f2bf(v.x); o.y = f2bf(v.y); o.z = f2bf(v.z); o.w = f2bf(v.w);
    ((ushort4*)out)[i] = o;
}

// ---------------- fp32 [R][C] -> bf16 [C][R] (weight transpose+convert) ----------------
__global__ void k_transpose_cvt(const float* __restrict__ in, unsigned short* __restrict__ out,
                                int R, int C) {
    __shared__ float t[32][33];
    int c0 = blockIdx.x * 32, r0 = blockIdx.y * 32;
    int tx = threadIdx.x, ty = threadIdx.y;   // 32 x 8
#pragma unroll
    for (int i = 0; i < 4; ++i)
        t[ty + i*8][tx] = in[(size_t)(r0 + ty + i*8) * C + c0 + tx];
    __syncthreads();
#pragma unroll
    for (int i = 0; i < 4; ++i)
        out[(size_t)(c0 + ty + i*8) * R + r0 + tx] = f2bf(t[tx][ty + i*8]);
}

// ---------------- concat bq|bk|bv -> [3072] ----------------
__global__ void k_concat_bias(const float* __restrict__ bq, const float* __restrict__ bk,
                              const float* __restrict__ bv, float* __restrict__ out) {
    int i = blockIdx.x * 256 + threadIdx.x;
    if (i >= HQKV) return;
    out[i] = (i < H_) ? bq[i] : (i < H_ + KV_ ? bk[i - H_] : bv[i - H_ - KV_]);
}

// ---------------- V slice of QKV [B*S][3072] -> V^T [B][KV][S] ----------------
__global__ void k_transpose_v(const unsigned short* __restrict__ in, unsigned short* __restrict__ out) {
    __shared__ unsigned short t[32][33];
    int b = blockIdx.z;
    int c0 = blockIdx.x * 32, s0 = blockIdx.y * 32;
    int tx = threadIdx.x, ty = threadIdx.y;
#pragma unroll
    for (int i = 0; i < 4; ++i)
        t[ty + i*8][tx] = in[((size_t)b * S_ + s0 + ty + i*8) * HQKV + (H_ + KV_) + c0 + tx];
    __syncthreads();
#pragma unroll
    for (int i = 0; i < 4; ++i)
        out[((size_t)b * KV_ + c0 + ty + i*8) * S_ + s0 + tx] = t[tx][ty + i*8];
}

// ---------------- bf16 GEMM: C[M,N] = A[M,K] * Bt[N,K]^T + bias ----------------
#define GLDS16(gsrc, ldst)                                                            \
    __builtin_amdgcn_global_load_lds(                                                 \
        (const __attribute__((address_space(1))) void*)(gsrc),                        \
        (__attribute__((address_space(3))) void*)(ldst), 16, 0, 0)

template <bool BF16OUT>
__global__ __launch_bounds__(256) void k_gemm_bt(
    const unsigned short* __restrict__ A, const unsigned short* __restrict__ Bt,
    const float* __restrict__ bias, void* __restrict__ Cout, int M, int N, int K) {
    __shared__ __align__(16) unsigned short As[128 * 64];
    __shared__ __align__(16) unsigned short Bs[128 * 64];
    const int tid = threadIdx.x, lane = tid & 63, w = tid >> 6;
    const int l15 = lane & 15, l4 = lane >> 4;
    const int wr = w >> 1, wc = w & 1;
    const int m0 = blockIdx.x * 128, n0 = blockIdx.y * 128;
    f32x4 acc[4][4] = {};

    for (int kt = 0; kt < K; kt += 64) {
        __syncthreads();
#pragma unroll
        for (int i = 0; i < 4; ++i) {
            int p = (w * 4 + i) * 64 + lane;
            int row = p >> 3, c = (p & 7) ^ (row & 7);
            GLDS16(A + (size_t)(m0 + row) * K + kt + c * 8, As + (size_t)(w * 4 + i) * 512);
        }
#pragma unroll
        for (int i = 0; i < 4; ++i) {
            int p = (w * 4 + i) * 64 + lane;
            int row = p >> 3, c = (p & 7) ^ (row & 7);
            GLDS16(Bt + (size_t)(n0 + row) * K + kt + c * 8, Bs + (size_t)(w * 4 + i) * 512);
        }
        __syncthreads();
#pragma unroll
        for (int ks = 0; ks < 2; ++ks) {
            bf16x8 af[4], bfr[4];
#pragma unroll
            for (int m = 0; m < 4; ++m) {
                int row = wr * 64 + m * 16 + l15;
                int ch = (ks * 4 + l4) ^ (row & 7);
                af[m] = *(const bf16x8*)(As + row * 64 + ch * 8);
            }
#pragma unroll
            for (int n = 0; n < 4; ++n) {
                int row = wc * 64 + n * 16 + l15;
                int ch = (ks * 4 + l4) ^ (row & 7);
                bfr[n] = *(const bf16x8*)(Bs + row * 64 + ch * 8);
            }
#pragma unroll
            for (int m = 0; m < 4; ++m)
#pragma unroll
                for (int n = 0; n < 4; ++n)
                    acc[m][n] = __builtin_amdgcn_mfma_f32_16x16x32_bf16(af[m], bfr[n], acc[m][n], 0, 0, 0);
        }
    }
#pragma unroll
    for (int m = 0; m < 4; ++m) {
        int row = m0 + wr * 64 + m * 16 + l4 * 4;
#pragma unroll
        for (int n = 0; n < 4; ++n) {
            int col = n0 + wc * 64 + n * 16 + l15;
            float bv = bias[col];
#pragma unroll
            for (int r = 0; r < 4; ++r) {
                float v = acc[m][n][r] + bv;
                if (BF16OUT)
                    ((unsigned short*)Cout)[(size_t)(row + r) * N + col] = f2bf(v);
                else
                    ((float*)Cout)[(size_t)(row + r) * N + col] = v;
            }
        }
    }
}

// ---------------- causal GQA flash attention (balanced pairing) ----------------
// QBLK=64 (4 waves x 16 rows), KBLK=64, D=128. Block pr handles q-tiles {pr, 31-pr}:
// (pr+1) + (32-pr) = 33 k-tile iterations per block -> perfectly uniform grid.
__global__ __launch_bounds__(256) void k_flash(
    const unsigned short* __restrict__ QKV,  // [B*S][3072]  Q|K|V
    const unsigned short* __restrict__ VT,   // [B][KV][S]
    unsigned short* __restrict__ Oa) {       // [B*S][H]
    __shared__ __align__(16) unsigned short Ks[64][132];    // K tile [k][d]
    __shared__ __align__(16) unsigned short Vs[128][68];    // V^T tile [d][k]
    __shared__ __align__(16) unsigned short Ps[4][16][68];  // per-wave P [q][k]
    const int tid = threadIdx.x, lane = tid & 63, w = tid >> 6;
    const int l15 = lane & 15, l4 = lane >> 4;
    const int pr = blockIdx.x;               // 0..15 pair index
    const int bh = blockIdx.y;               // 0..31
    const int b = bh >> 4, nh = bh & 15, g = nh >> 2;
    // exp2-domain: fold 1/sqrt(128) * log2(e) into the score scale
    const float sc2 = 0.08838834764831843f * 1.4426950408889634f;

    for (int half = 0; half < 2; ++half) {
        const int qt = half ? (31 - pr) : pr;
        const int q0 = qt * 64;
        const int qbase = q0 + w * 16;

        bf16x8 qf[4];
#pragma unroll
        for (int kb = 0; kb < 4; ++kb)
            qf[kb] = *(const bf16x8*)(QKV + (size_t)(b * S_ + qbase + l15) * HQKV +
                                      nh * HD_ + kb * 32 + l4 * 8);

        f32x4 o[8] = {};
        float mrow[4], lrow[4];
#pragma unroll
        for (int r = 0; r < 4; ++r) { mrow[r] = -1e30f; lrow[r] = 0.f; }

        const int nkt = qt + 1;
        for (int kt = 0; kt < nkt; ++kt) {
            const int kv0 = kt * 64;
            __syncthreads();   // previous tile fully consumed (also guards across halves)
            // stage K tile [64][128]: 1024 16B chunks
#pragma unroll
            for (int i = 0; i < 4; ++i) {
                int f = i * 256 + tid;
                int row = f >> 4, c = f & 15;
                *(bf16x8*)(&Ks[row][c * 8]) =
                    *(const bf16x8*)(QKV + (size_t)(b * S_ + kv0 + row) * HQKV + H_ + g * HD_ + c * 8);
            }
            // stage V^T tile [128][64]: 1024 16B chunks
#pragma unroll
            for (int i = 0; i < 4; ++i) {
                int f = i * 256 + tid;
                int row = f >> 3, c = f & 7;
                *(bf16x8*)(&Vs[row][c * 8]) =
                    *(const bf16x8*)(VT + ((size_t)b * KV_ + g * HD_ + row) * S_ + kv0 + c * 8);
            }
            __syncthreads();

            // S = Q K^T
            f32x4 s[4] = {};
#pragma unroll
            for (int kb = 0; kb < 4; ++kb) {
                bf16x8 kf[4];
#pragma unroll
                for (int n = 0; n < 4; ++n)
                    kf[n] = *(const bf16x8*)(&Ks[n * 16 + l15][kb * 32 + l4 * 8]);
#pragma unroll
                for (int n = 0; n < 4; ++n)
                    s[n] = __builtin_amdgcn_mfma_f32_16x16x32_bf16(qf[kb], kf[n], s[n], 0, 0, 0);
            }
            // scale (+ causal mask only on the wave's diagonal tile)
            if (kv0 + 63 > qbase) {
#pragma unroll
                for (int n = 0; n < 4; ++n)
#pragma unroll
                    for (int r = 0; r < 4; ++r) {
                        int kcol = kv0 + n * 16 + l15;
                        int qrow = qbase + l4 * 4 + r;
                        s[n][r] = (kcol <= qrow) ? s[n][r] * sc2 : -1e30f;
                    }
            } else {
#pragma unroll
                for (int n = 0; n < 4; ++n)
#pragma unroll
                    for (int r = 0; r < 4; ++r) s[n][r] *= sc2;
            }
            // online softmax (exp2 domain); row = 16-lane group (col=l15)
            float sf[4];
#pragma unroll
            for (int r = 0; r < 4; ++r) {
                float vm = fmaxf(fmaxf(s[0][r], s[1][r]), fmaxf(s[2][r], s[3][r]));
                vm = fmaxf(vm, __shfl_xor(vm, 1));
                vm = fmaxf(vm, __shfl_xor(vm, 2));
                vm = fmaxf(vm, __shfl_xor(vm, 4));
                vm = fmaxf(vm, __shfl_xor(vm, 8));
                float mn = fmaxf(mrow[r], vm);
                sf[r] = exp2f(mrow[r] - mn);
                mrow[r] = mn;
            }
            float rs[4] = {0.f, 0.f, 0.f, 0.f};
#pragma unroll
            for (int n = 0; n < 4; ++n)
#pragma unroll
                for (int r = 0; r < 4; ++r) {
                    float p = exp2f(s[n][r] - mrow[r]);
                    s[n][r] = p;
                    rs[r] += p;
                }
#pragma unroll
            for (int r = 0; r < 4; ++r) {
                float t = rs[r];
                t += __shfl_xor(t, 1); t += __shfl_xor(t, 2);
                t += __shfl_xor(t, 4); t += __shfl_xor(t, 8);
                lrow[r] = lrow[r] * sf[r] + t;
            }
#pragma unroll
            for (int nc = 0; nc < 8; ++nc) {
                f32x4 t = o[nc];
                t[0] *= sf[0]; t[1] *= sf[1]; t[2] *= sf[2]; t[3] *= sf[3];
                o[nc] = t;
            }
            // P -> per-wave LDS (stride 68: conflict-free scalar u16 writes)
#pragma unroll
            for (int n = 0; n < 4; ++n)
#pragma unroll
                for (int r = 0; r < 4; ++r)
                    Ps[w][l4 * 4 + r][n * 16 + l15] = f2bf(s[n][r]);
            // O += P V
#pragma unroll
            for (int kb = 0; kb < 2; ++kb) {
                bf16x8 pf = *(const bf16x8*)(&Ps[w][l15][kb * 32 + l4 * 8]);
#pragma unroll
                for (int nc = 0; nc < 8; ++nc) {
                    bf16x8 vf = *(const bf16x8*)(&Vs[nc * 16 + l15][kb * 32 + l4 * 8]);
                    o[nc] = __builtin_amdgcn_mfma_f32_16x16x32_bf16(pf, vf, o[nc], 0, 0, 0);
                }
            }
        }
        // epilogue
#pragma unroll
        for (int r = 0; r < 4; ++r) {
            float inv = 1.0f / lrow[r];
            int qrow = qbase + l4 * 4 + r;
            size_t base = (size_t)(b * S_ + qrow) * H_ + nh * HD_;
#pragma unroll
            for (int nc = 0; nc < 8; ++nc)
                Oa[base + nc * 16 + l15] = f2bf(o[nc][r] * inv);
        }
    }
}

// ---------------- launch ----------------
extern "C" void kernel_launch(void* const* d_in, const int* in_sizes, int n_in,
                              void* d_out, int out_size, void* d_ws, size_t ws_size,
                              hipStream_t stream) {
    const float* X  = (const float*)d_in[0];
    const float* Wq = (const float*)d_in[1];
    const float* bq = (const float*)d_in[2];
    const float* Wk = (const float*)d_in[3];
    const float* bk = (const float*)d_in[4];
    const float* Wv = (const float*)d_in[5];
    const float* bv = (const float*)d_in[6];
    const float* Wo = (const float*)d_in[7];
    const float* bo = (const float*)d_in[8];
    float* out = (float*)d_out;

    if (ws_size < 67200000) return;
    char* ws = (char*)d_ws;
    unsigned short* Xb   = (unsigned short*)(ws);              // 16.78 MB; reused as AOb
    unsigned short* WqkvT= (unsigned short*)(ws + 16777216);   // [3072][2048] 12.58 MB
    unsigned short* WoT  = (unsigned short*)(ws + 29360128);   // 8.39 MB
    unsigned short* QKV  = (unsigned short*)(ws + 37748736);   // [4096][3072] 25.17 MB
    unsigned short* VbT  = (unsigned short*)(ws + 62914560);   // 4.19 MB
    float*          bqkv = (float*)(ws + 67108864);            // 12 KB
    unsigned short* AOb  = Xb;                                 // Xb dead after QKV GEMM

    k_cvt_bf16<<<(B_ * S_ * H_ / 4 + 255) / 256, 256, 0, stream>>>(X, Xb, B_ * S_ * H_ / 4);
    k_transpose_cvt<<<dim3(H_ / 32, H_ / 32), dim3(32, 8), 0, stream>>>(Wq, WqkvT, H_, H_);
    k_transpose_cvt<<<dim3(KV_ / 32, H_ / 32), dim3(32, 8), 0, stream>>>(Wk, WqkvT + (size_t)H_ * H_, H_, KV_);
    k_transpose_cvt<<<dim3(KV_ / 32, H_ / 32), dim3(32, 8), 0, stream>>>(Wv, WqkvT + (size_t)(H_ + KV_) * H_, H_, KV_);
    k_transpose_cvt<<<dim3(H_ / 32, H_ / 32), dim3(32, 8), 0, stream>>>(Wo, WoT, H_, H_);
    k_concat_bias<<<(HQKV + 255) / 256, 256, 0, stream>>>(bq, bk, bv, bqkv);

    // fused QKV projection: [4096,2048] x [3072,2048]^T -> [4096,3072]
    k_gemm_bt<true><<<dim3(32, 24), 256, 0, stream>>>(Xb, WqkvT, bqkv, QKV, 4096, HQKV, 2048);

    k_transpose_v<<<dim3(KV_ / 32, S_ / 32, B_), dim3(32, 8), 0, stream>>>(QKV, VbT);
    k_flash<<<dim3(16, 32), 256, 0, stream>>>(QKV, VbT, AOb);

    k_gemm_bt<false><<<dim3(32, 16), 256, 0, stream>>>(AOb, WoT, bo, out, 4096, 2048, 2048);
}

// Round 3
// 240.266 us; speedup vs baseline: 1.5678x; 1.0723x over previous
//
#include <hip/hip_runtime.h>

// Problem constants
#define B_   2
#define S_   2048
#define H_   2048
#define NH_  16
#define G_   4
#define HD_  128
#define KV_  512
#define HQKV 3072   // fused Q|K|V output width

typedef __attribute__((ext_vector_type(8))) short bf16x8;
typedef __attribute__((ext_vector_type(4))) float f32x4;

__device__ __forceinline__ unsigned short f2bf(float f) {
    unsigned u = __float_as_uint(f);
    u += 0x7fff + ((u >> 16) & 1);   // RNE
    return (unsigned short)(u >> 16);
}
__device__ __forceinline__ float bf2f(unsigned short s) {
    return __uint_as_float(((unsigned)s) << 16);
}

#define GLDS16(gsrc, ldst)                                                            \
    __builtin_amdgcn_global_load_lds(                                                 \
        (const __attribute__((address_space(1))) void*)(gsrc),                        \
        (__attribute__((address_space(3))) void*)(ldst), 16, 0, 0)

// ---------------- fp32 -> bf16 elementwise ----------------
__global__ void k_cvt_bf16(const float* __restrict__ in, unsigned short* __restrict__ out, int n4) {
    int i = blockIdx.x * blockDim.x + threadIdx.x;
    if (i >= n4) return;
    float4 v = ((const float4*)in)[i];
    ushort4 o;
    o.x = f2bf(v.x); o.y = f2bf(v.y); o.z = f2bf(v.z); o.w = f2bf(v.w);
    ((ushort4*)out)[i] = o;
}

// ---------------- fp32 [R][C] -> bf16 [C][R] (weight transpose+convert) ----------------
__global__ void k_transpose_cvt(const float* __restrict__ in, unsigned short* __restrict__ out,
                                int R, int C) {
    __shared__ float t[32][33];
    int c0 = blockIdx.x * 32, r0 = blockIdx.y * 32;
    int tx = threadIdx.x, ty = threadIdx.y;   // 32 x 8
#pragma unroll
    for (int i = 0; i < 4; ++i)
        t[ty + i*8][tx] = in[(size_t)(r0 + ty + i*8) * C + c0 + tx];
    __syncthreads();
#pragma unroll
    for (int i = 0; i < 4; ++i)
        out[(size_t)(c0 + ty + i*8) * R + r0 + tx] = f2bf(t[tx][ty + i*8]);
}

// ---------------- concat bq|bk|bv -> [3072] ----------------
__global__ void k_concat_bias(const float* __restrict__ bq, const float* __restrict__ bk,
                              const float* __restrict__ bv, float* __restrict__ out) {
    int i = blockIdx.x * 256 + threadIdx.x;
    if (i >= HQKV) return;
    out[i] = (i < H_) ? bq[i] : (i < H_ + KV_ ? bk[i - H_] : bv[i - H_ - KV_]);
}

// ---------------- V slice of QKV [B*S][3072] -> V^T [B][KV][S] ----------------
__global__ void k_transpose_v(const unsigned short* __restrict__ in, unsigned short* __restrict__ out) {
    __shared__ unsigned short t[32][33];
    int b = blockIdx.z;
    int c0 = blockIdx.x * 32, s0 = blockIdx.y * 32;
    int tx = threadIdx.x, ty = threadIdx.y;
#pragma unroll
    for (int i = 0; i < 4; ++i)
        t[ty + i*8][tx] = in[((size_t)b * S_ + s0 + ty + i*8) * HQKV + (H_ + KV_) + c0 + tx];
    __syncthreads();
#pragma unroll
    for (int i = 0; i < 4; ++i)
        out[((size_t)b * KV_ + c0 + ty + i*8) * S_ + s0 + tx] = t[tx][ty + i*8];
}

// ---------------- bf16 GEMM: C[M,N] = A[M,K] * Bt[N,K]^T + bias ----------------
template <bool BF16OUT>
__global__ __launch_bounds__(256) void k_gemm_bt(
    const unsigned short* __restrict__ A, const unsigned short* __restrict__ Bt,
    const float* __restrict__ bias, void* __restrict__ Cout, int M, int N, int K) {
    __shared__ __align__(16) unsigned short As[128 * 64];
    __shared__ __align__(16) unsigned short Bs[128 * 64];
    const int tid = threadIdx.x, lane = tid & 63, w = tid >> 6;
    const int l15 = lane & 15, l4 = lane >> 4;
    const int wr = w >> 1, wc = w & 1;
    const int m0 = blockIdx.x * 128, n0 = blockIdx.y * 128;
    f32x4 acc[4][4] = {};

    for (int kt = 0; kt < K; kt += 64) {
        __syncthreads();
#pragma unroll
        for (int i = 0; i < 4; ++i) {
            int p = (w * 4 + i) * 64 + lane;
            int row = p >> 3, c = (p & 7) ^ (row & 7);
            GLDS16(A + (size_t)(m0 + row) * K + kt + c * 8, As + (size_t)(w * 4 + i) * 512);
        }
#pragma unroll
        for (int i = 0; i < 4; ++i) {
            int p = (w * 4 + i) * 64 + lane;
            int row = p >> 3, c = (p & 7) ^ (row & 7);
            GLDS16(Bt + (size_t)(n0 + row) * K + kt + c * 8, Bs + (size_t)(w * 4 + i) * 512);
        }
        __syncthreads();
#pragma unroll
        for (int ks = 0; ks < 2; ++ks) {
            bf16x8 af[4], bfr[4];
#pragma unroll
            for (int m = 0; m < 4; ++m) {
                int row = wr * 64 + m * 16 + l15;
                int ch = (ks * 4 + l4) ^ (row & 7);
                af[m] = *(const bf16x8*)(As + row * 64 + ch * 8);
            }
#pragma unroll
            for (int n = 0; n < 4; ++n) {
                int row = wc * 64 + n * 16 + l15;
                int ch = (ks * 4 + l4) ^ (row & 7);
                bfr[n] = *(const bf16x8*)(Bs + row * 64 + ch * 8);
            }
#pragma unroll
            for (int m = 0; m < 4; ++m)
#pragma unroll
                for (int n = 0; n < 4; ++n)
                    acc[m][n] = __builtin_amdgcn_mfma_f32_16x16x32_bf16(af[m], bfr[n], acc[m][n], 0, 0, 0);
        }
    }
#pragma unroll
    for (int m = 0; m < 4; ++m) {
        int row = m0 + wr * 64 + m * 16 + l4 * 4;
#pragma unroll
        for (int n = 0; n < 4; ++n) {
            int col = n0 + wc * 64 + n * 16 + l15;
            float bv = bias[col];
#pragma unroll
            for (int r = 0; r < 4; ++r) {
                float v = acc[m][n][r] + bv;
                if (BF16OUT)
                    ((unsigned short*)Cout)[(size_t)(row + r) * N + col] = f2bf(v);
                else
                    ((float*)Cout)[(size_t)(row + r) * N + col] = v;
            }
        }
    }
}

// ---------------- causal GQA flash attention ----------------
// QBLK=64 (4 waves x 16 rows), KBLK=64. Balanced pairing: block handles q-tiles
// {pr, 31-pr} = uniform 33 k-tiles. K/V staged via global_load_lds (w=16) into
// double-buffered LDS with both-sides chunk-XOR swizzle; next tile's loads are
// issued before compute and survive a raw s_barrier (drained once per tile).
// XCD swizzle: each XCD's 64 blocks share one (b,g) -> KV L2-resident.
__global__ __launch_bounds__(256) void k_flash(
    const unsigned short* __restrict__ QKV,  // [B*S][3072]  Q|K|V
    const unsigned short* __restrict__ VT,   // [B][KV][S]
    unsigned short* __restrict__ Oa) {       // [B*S][H]
    __shared__ __align__(16) unsigned short Ks[2][64 * 128];   // [k][d], chunk-swizzled
    __shared__ __align__(16) unsigned short Vs[2][128 * 64];   // [d][k], chunk-swizzled
    __shared__ __align__(16) unsigned short Ps[4][16][68];     // per-wave P [q][k]
    const int tid = threadIdx.x, lane = tid & 63, w = tid >> 6;
    const int l15 = lane & 15, l4 = lane >> 4;
    const int bid = blockIdx.x;              // 0..511
    const int xcd = bid & 7, idx = bid >> 3; // per-XCD index 0..63
    const int bh = xcd * 4 + (idx & 3);      // 4 consecutive heads per XCD = one (b,g)
    const int pr = idx >> 2;                 // 0..15 pair index
    const int b = bh >> 4, nh = bh & 15, g = nh >> 2;
    const float sc2 = 0.08838834764831843f * 1.4426950408889634f;  // 1/sqrt(128)*log2(e)

    const unsigned short* kgbase = QKV + (size_t)b * S_ * HQKV + H_ + g * HD_;
    const unsigned short* vgbase = VT + ((size_t)b * KV_ + g * HD_) * S_;

    for (int half = 0; half < 2; ++half) {
        const int qt = half ? (31 - pr) : pr;
        const int q0 = qt * 64;
        const int qbase = q0 + w * 16;

        // Q fragments in regs, pre-scaled by sc2 (removes per-tile scale mul)
        bf16x8 qf[4];
#pragma unroll
        for (int kb = 0; kb < 4; ++kb) {
            bf16x8 raw = *(const bf16x8*)(QKV + (size_t)(b * S_ + qbase + l15) * HQKV +
                                          nh * HD_ + kb * 32 + l4 * 8);
            bf16x8 sq;
#pragma unroll
            for (int e = 0; e < 8; ++e)
                sq[e] = (short)f2bf(bf2f((unsigned short)raw[e]) * sc2);
            qf[kb] = sq;
        }

        f32x4 o[8] = {};
        float mrow[4], lrow[4];
#pragma unroll
        for (int r = 0; r < 4; ++r) { mrow[r] = -1e30f; lrow[r] = 0.f; }

        // issue one K/V tile's global_load_lds into buffer cb (8 instrs/thread, no regs)
        auto issue = [&](int kt, int cb) {
            const int kv0 = kt * 64;
#pragma unroll
            for (int i = 0; i < 4; ++i) {
                int p = i * 256 + tid;                        // K chunk 0..1023
                int row = p >> 4, c = (p & 15) ^ (row & 15);  // pre-swizzled source
                GLDS16(kgbase + (size_t)(kv0 + row) * HQKV + c * 8,
                       &Ks[cb][(i * 256 + w * 64) * 8]);
            }
#pragma unroll
            for (int i = 0; i < 4; ++i) {
                int p = i * 256 + tid;                        // V chunk 0..1023
                int row = p >> 3, c = (p & 7) ^ (row & 7);
                GLDS16(vgbase + (size_t)row * S_ + kv0 + c * 8,
                       &Vs[cb][(i * 256 + w * 64) * 8]);
            }
        };

        auto compute = [&](int cb, int kt) {
            const int kv0 = kt * 64;
            // S = Q K^T (kf via swizzled ds_read)
            f32x4 s[4] = {};
#pragma unroll
            for (int kb = 0; kb < 4; ++kb) {
                bf16x8 kf[4];
#pragma unroll
                for (int n = 0; n < 4; ++n) {
                    int row = n * 16 + l15;
                    int sl = (kb * 4 + l4) ^ (row & 15);
                    kf[n] = *(const bf16x8*)(&Ks[cb][(row * 16 + sl) * 8]);
                }
#pragma unroll
                for (int n = 0; n < 4; ++n)
                    s[n] = __builtin_amdgcn_mfma_f32_16x16x32_bf16(qf[kb], kf[n], s[n], 0, 0, 0);
            }
            // causal mask only on this wave's diagonal tile
            if (kv0 + 63 > qbase) {
#pragma unroll
                for (int n = 0; n < 4; ++n)
#pragma unroll
                    for (int r = 0; r < 4; ++r) {
                        int kcol = kv0 + n * 16 + l15;
                        int qrow = qbase + l4 * 4 + r;
                        if (kcol > qrow) s[n][r] = -1e30f;
                    }
            }
            // online softmax (exp2 domain) with defer-max (T13, THR=8)
            float vm[4];
#pragma unroll
            for (int r = 0; r < 4; ++r) {
                float v = fmaxf(fmaxf(s[0][r], s[1][r]), fmaxf(s[2][r], s[3][r]));
                v = fmaxf(v, __shfl_xor(v, 1));
                v = fmaxf(v, __shfl_xor(v, 2));
                v = fmaxf(v, __shfl_xor(v, 4));
                v = fmaxf(v, __shfl_xor(v, 8));
                vm[r] = v;
            }
            int needs = 0;
#pragma unroll
            for (int r = 0; r < 4; ++r) needs |= (vm[r] > mrow[r] + 8.0f) ? 1 : 0;
            if (__any(needs)) {
                float sf[4];
#pragma unroll
                for (int r = 0; r < 4; ++r) {
                    float mn = fmaxf(mrow[r], vm[r]);
                    sf[r] = exp2f(mrow[r] - mn);
                    mrow[r] = mn;
                    lrow[r] *= sf[r];
                }
#pragma unroll
                for (int nc = 0; nc < 8; ++nc) {
                    f32x4 t = o[nc];
                    t[0] *= sf[0]; t[1] *= sf[1]; t[2] *= sf[2]; t[3] *= sf[3];
                    o[nc] = t;
                }
            }
            float rs[4] = {0.f, 0.f, 0.f, 0.f};
#pragma unroll
            for (int n = 0; n < 4; ++n)
#pragma unroll
                for (int r = 0; r < 4; ++r) {
                    float p = exp2f(s[n][r] - mrow[r]);
                    s[n][r] = p;
                    rs[r] += p;
                }
#pragma unroll
            for (int r = 0; r < 4; ++r) {
                float t = rs[r];
                t += __shfl_xor(t, 1); t += __shfl_xor(t, 2);
                t += __shfl_xor(t, 4); t += __shfl_xor(t, 8);
                lrow[r] += t;
            }
            // P -> per-wave LDS (C-layout scatter)
#pragma unroll
            for (int n = 0; n < 4; ++n)
#pragma unroll
                for (int r = 0; r < 4; ++r)
                    Ps[w][l4 * 4 + r][n * 16 + l15] = f2bf(s[n][r]);
            // O += P V (vf via swizzled ds_read)
#pragma unroll
            for (int kb = 0; kb < 2; ++kb) {
                bf16x8 pf = *(const bf16x8*)(&Ps[w][l15][kb * 32 + l4 * 8]);
#pragma unroll
                for (int nc = 0; nc < 8; ++nc) {
                    int row = nc * 16 + l15;
                    int sl = (kb * 4 + l4) ^ (row & 7);
                    bf16x8 vf = *(const bf16x8*)(&Vs[cb][(row * 8 + sl) * 8]);
                    o[nc] = __builtin_amdgcn_mfma_f32_16x16x32_bf16(pf, vf, o[nc], 0, 0, 0);
                }
            }
        };

        const int nkt = qt + 1;
        // prologue: full-drain guard (previous half), then load tile 0
        __syncthreads();
        issue(0, 0);
        asm volatile("s_waitcnt vmcnt(0)" ::: "memory");
        __builtin_amdgcn_s_barrier();
        __builtin_amdgcn_sched_barrier(0);

        for (int kt = 0; kt < nkt; ++kt) {
            const int cb = kt & 1;
            if (kt + 1 < nkt) issue(kt + 1, cb ^ 1);  // prefetch overlaps compute
            compute(cb, kt);
            asm volatile("s_waitcnt vmcnt(0) lgkmcnt(0)" ::: "memory");
            __builtin_amdgcn_s_barrier();
            __builtin_amdgcn_sched_barrier(0);
        }

        // epilogue
#pragma unroll
        for (int r = 0; r < 4; ++r) {
            float inv = 1.0f / lrow[r];
            int qrow = qbase + l4 * 4 + r;
            size_t base = (size_t)(b * S_ + qrow) * H_ + nh * HD_;
#pragma unroll
            for (int nc = 0; nc < 8; ++nc)
                Oa[base + nc * 16 + l15] = f2bf(o[nc][r] * inv);
        }
    }
}

// ---------------- launch ----------------
extern "C" void kernel_launch(void* const* d_in, const int* in_sizes, int n_in,
                              void* d_out, int out_size, void* d_ws, size_t ws_size,
                              hipStream_t stream) {
    const float* X  = (const float*)d_in[0];
    const float* Wq = (const float*)d_in[1];
    const float* bq = (const float*)d_in[2];
    const float* Wk = (const float*)d_in[3];
    const float* bk = (const float*)d_in[4];
    const float* Wv = (const float*)d_in[5];
    const float* bv = (const float*)d_in[6];
    const float* Wo = (const float*)d_in[7];
    const float* bo = (const float*)d_in[8];
    float* out = (float*)d_out;

    if (ws_size < 67200000) return;
    char* ws = (char*)d_ws;
    unsigned short* Xb   = (unsigned short*)(ws);              // 16.78 MB; reused as AOb
    unsigned short* WqkvT= (unsigned short*)(ws + 16777216);   // [3072][2048] 12.58 MB
    unsigned short* WoT  = (unsigned short*)(ws + 29360128);   // 8.39 MB
    unsigned short* QKV  = (unsigned short*)(ws + 37748736);   // [4096][3072] 25.17 MB
    unsigned short* VbT  = (unsigned short*)(ws + 62914560);   // 4.19 MB
    float*          bqkv = (float*)(ws + 67108864);            // 12 KB
    unsigned short* AOb  = Xb;                                 // Xb dead after QKV GEMM

    k_cvt_bf16<<<(B_ * S_ * H_ / 4 + 255) / 256, 256, 0, stream>>>(X, Xb, B_ * S_ * H_ / 4);
    k_transpose_cvt<<<dim3(H_ / 32, H_ / 32), dim3(32, 8), 0, stream>>>(Wq, WqkvT, H_, H_);
    k_transpose_cvt<<<dim3(KV_ / 32, H_ / 32), dim3(32, 8), 0, stream>>>(Wk, WqkvT + (size_t)H_ * H_, H_, KV_);
    k_transpose_cvt<<<dim3(KV_ / 32, H_ / 32), dim3(32, 8), 0, stream>>>(Wv, WqkvT + (size_t)(H_ + KV_) * H_, H_, KV_);
    k_transpose_cvt<<<dim3(H_ / 32, H_ / 32), dim3(32, 8), 0, stream>>>(Wo, WoT, H_, H_);
    k_concat_bias<<<(HQKV + 255) / 256, 256, 0, stream>>>(bq, bk, bv, bqkv);

    // fused QKV projection: [4096,2048] x [3072,2048]^T -> [4096,3072]
    k_gemm_bt<true><<<dim3(32, 24), 256, 0, stream>>>(Xb, WqkvT, bqkv, QKV, 4096, HQKV, 2048);

    k_transpose_v<<<dim3(KV_ / 32, S_ / 32, B_), dim3(32, 8), 0, stream>>>(QKV, VbT);
    k_flash<<<dim3(512), 256, 0, stream>>>(QKV, VbT, AOb);

    k_gemm_bt<false><<<dim3(32, 16), 256, 0, stream>>>(AOb, WoT, bo, out, 4096, 2048, 2048);
}